// Round 1
// baseline (164.520 us; speedup 1.0000x reference)
//
#include <hip/hip_runtime.h>
#include <hip/hip_bf16.h>

#define NV 100000
#define ND 64
#define NB 4096
#define NL 200

typedef __bf16 bf16_t;
typedef __bf16 bf16x8 __attribute__((ext_vector_type(8)));
typedef float f32x4 __attribute__((ext_vector_type(4)));

#define HSTRIDE 72   // bf16 elems per hist row (64 + 8 pad): frag reads 2-way-bank only
#define MT 13        // m-tiles of 16 rows -> 208 (200 real + 8 zero pad)

__global__ __launch_bounds__(256)
void din_kernel1(const int* __restrict__ item_ids,
                 const int* __restrict__ history,
                 const int* __restrict__ hist_len,
                 const float* __restrict__ emb,
                 const float* __restrict__ aW1,
                 const float* __restrict__ ab1,
                 const float* __restrict__ aW2,
                 float* __restrict__ comb_ws)
{
    __shared__ __align__(16) bf16_t histA[208 * HSTRIDE];
    __shared__ __align__(16) bf16_t wbT[64 * HSTRIDE];   // transposed: wbT[n][k]
    __shared__ float tgt[64];
    __shared__ float cb[64];
    __shared__ __align__(16) float scores[208];
    __shared__ float wts[208];
    __shared__ float pp[4 * 64];
    __shared__ float red[8];
    __shared__ float pooled[64];

    const int b   = blockIdx.x;
    const int tid = threadIdx.x;
    const int len = hist_len[b];

    // ---- phase 1: load target row + gather history -> bf16 LDS (masked) ----
    if (tid < 64) tgt[tid] = emb[(long)item_ids[b] * ND + tid];

    {
        const int p     = tid & 3;    // quarter of a row: 16 floats
        const int lbase = tid >> 2;   // 64 rows per pass
        for (int pass = 0; pass < 4; ++pass) {
            int l = pass * 64 + lbase;
            if (l < 208) {
                bf16x8 o0 = (bf16x8)(bf16_t)0.f;
                bf16x8 o1 = (bf16x8)(bf16_t)0.f;
                if (l < NL && l < len) {
                    int idx = history[b * NL + l];
                    const float* src = emb + (long)idx * ND + p * 16;
                    f32x4 a0 = *(const f32x4*)(src);
                    f32x4 a1 = *(const f32x4*)(src + 4);
                    f32x4 a2 = *(const f32x4*)(src + 8);
                    f32x4 a3 = *(const f32x4*)(src + 12);
                    for (int i = 0; i < 4; ++i) {
                        o0[i]     = (bf16_t)a0[i];
                        o0[i + 4] = (bf16_t)a1[i];
                        o1[i]     = (bf16_t)a2[i];
                        o1[i + 4] = (bf16_t)a3[i];
                    }
                }
                bf16_t* dst = &histA[l * HSTRIDE + p * 16];
                *(bf16x8*)(dst)     = o0;
                *(bf16x8*)(dst + 8) = o1;
            }
        }
    }
    __syncthreads();

    // ---- phase 2: build Wb^T (bf16) and c_b ----
    {
        const int n  = tid & 63;
        const int kp = tid >> 6;    // 0..3
        float csum = 0.f;
        for (int i = 0; i < 16; ++i) {
            int k = kp * 16 + i;                 // wave-uniform
            float tk = tgt[k];                   // LDS broadcast
            float w  = aW1[k * 64 + n] + tk * aW1[(128 + k) * 64 + n];
            wbT[n * HSTRIDE + k] = (bf16_t)w;
            csum += tk * aW1[(64 + k) * 64 + n];
        }
        pp[kp * 64 + n] = csum;
    }
    __syncthreads();
    if (tid < 64) cb[tid] = ab1[tid] + pp[tid] + pp[64 + tid] + pp[128 + tid] + pp[192 + tid];
    __syncthreads();

    // ---- phase 3: H = hist @ Wb via MFMA; relu; dot aW2 -> scores ----
    {
        const int wave = tid >> 6;
        const int lane = tid & 63;
        const int col  = lane & 15;   // = m for A, = n for B, = col for C
        const int quad = lane >> 4;

        bf16x8 bfrag[4][2];
        for (int nt = 0; nt < 4; ++nt)
            for (int kb = 0; kb < 2; ++kb)
                bfrag[nt][kb] = *(const bf16x8*)&wbT[(nt * 16 + col) * HSTRIDE + kb * 32 + quad * 8];
        float cvals[4], a2vals[4];
        for (int nt = 0; nt < 4; ++nt) {
            cvals[nt]  = cb[nt * 16 + col];
            a2vals[nt] = aW2[nt * 16 + col];
        }

        for (int mt = wave; mt < MT; mt += 4) {
            const bf16_t* arow = &histA[(mt * 16 + col) * HSTRIDE + quad * 8];
            bf16x8 af0 = *(const bf16x8*)(arow);
            bf16x8 af1 = *(const bf16x8*)(arow + 32);
            float sc[4] = {0.f, 0.f, 0.f, 0.f};
            for (int nt = 0; nt < 4; ++nt) {
                f32x4 acc = {0.f, 0.f, 0.f, 0.f};
                acc = __builtin_amdgcn_mfma_f32_16x16x32_bf16(af0, bfrag[nt][0], acc, 0, 0, 0);
                acc = __builtin_amdgcn_mfma_f32_16x16x32_bf16(af1, bfrag[nt][1], acc, 0, 0, 0);
                for (int i = 0; i < 4; ++i) {
                    float h = acc[i] + cvals[nt];
                    h = h > 0.f ? h : 0.f;
                    sc[i] += h * a2vals[nt];
                }
            }
            // reduce across the 16 cols (low 4 lane bits)
            for (int off = 1; off < 16; off <<= 1)
                for (int i = 0; i < 4; ++i)
                    sc[i] += __shfl_xor(sc[i], off, 64);
            if (col == 0) {
                f32x4 outv = {sc[0], sc[1], sc[2], sc[3]};   // rows quad*4+0..3
                *(f32x4*)&scores[mt * 16 + quad * 4] = outv;
            }
        }
    }
    __syncthreads();

    // ---- phase 4: softmax over exactly L=200 ----
    {
        float s = (tid < NL) ? scores[tid] : -1e30f;
        float m = s;
        for (int off = 32; off > 0; off >>= 1) m = fmaxf(m, __shfl_xor(m, off, 64));
        if ((tid & 63) == 0) red[tid >> 6] = m;
        __syncthreads();
        m = fmaxf(fmaxf(red[0], red[1]), fmaxf(red[2], red[3]));
        float e = (tid < NL) ? __expf(s - m) : 0.f;
        float ssum = e;
        for (int off = 32; off > 0; off >>= 1) ssum += __shfl_xor(ssum, off, 64);
        if ((tid & 63) == 0) red[4 + (tid >> 6)] = ssum;
        __syncthreads();
        float tot = red[4] + red[5] + red[6] + red[7];
        if (tid < NL) wts[tid] = e / tot;
    }
    __syncthreads();

    // ---- phase 5: pooled = sum_l w_l * hist_l ----
    {
        const int wave = tid >> 6, lane = tid & 63;
        float acc = 0.f;
        for (int i = 0; i < 50; ++i) {
            int l = wave * 50 + i;
            float wl = wts[l];                       // LDS broadcast
            acc += wl * (float)histA[l * HSTRIDE + lane];
        }
        pp[wave * 64 + lane] = acc;
    }
    __syncthreads();
    if (tid < 64) pooled[tid] = pp[tid] + pp[64 + tid] + pp[128 + tid] + pp[192 + tid];
    __syncthreads();

    // ---- phase 6: comb = [tgt, pooled, pooled - tgt] -> ws ----
    if (tid < 192) {
        float v;
        if (tid < 64)       v = tgt[tid];
        else if (tid < 128) v = pooled[tid - 64];
        else                v = pooled[tid - 128] - tgt[tid - 128];
        comb_ws[(long)b * 192 + tid] = v;
    }
}

__global__ __launch_bounds__(256)
void din_kernel2(const float* __restrict__ comb,
                 const float* __restrict__ fW1, const float* __restrict__ fb1,
                 const float* __restrict__ fW2, const float* __restrict__ fb2,
                 const float* __restrict__ fW3, const float* __restrict__ fb3,
                 float* __restrict__ out)
{
    __shared__ float z1s[16 * 130];   // stride 130: breaks 4-way bank conflict
    __shared__ float z2s[16 * 66];
    const int tid = threadIdx.x;
    const int r   = tid >> 4;         // 0..15 rows per block
    const int c   = tid & 15;
    const int row = blockIdx.x * 16 + r;

    // z1[j], j = c*8 + jj
    float acc[8];
    for (int jj = 0; jj < 8; ++jj) acc[jj] = fb1[c * 8 + jj];
    for (int i = 0; i < 192; ++i) {
        float cm = comb[(long)row * 192 + i];
        const float* wr = fW1 + i * 128 + c * 8;
        f32x4 w0 = *(const f32x4*)(wr);
        f32x4 w1 = *(const f32x4*)(wr + 4);
        for (int jj = 0; jj < 4; ++jj) {
            acc[jj]     += cm * w0[jj];
            acc[jj + 4] += cm * w1[jj];
        }
    }
    for (int jj = 0; jj < 8; ++jj) z1s[r * 130 + c * 8 + jj] = fmaxf(acc[jj], 0.f);
    __syncthreads();

    // z2[j], j = c*4 + jj
    float a2[4];
    for (int jj = 0; jj < 4; ++jj) a2[jj] = fb2[c * 4 + jj];
    for (int i = 0; i < 128; ++i) {
        float zv = z1s[r * 130 + i];
        f32x4 w = *(const f32x4*)(fW2 + i * 64 + c * 4);
        for (int jj = 0; jj < 4; ++jj) a2[jj] += zv * w[jj];
    }
    for (int jj = 0; jj < 4; ++jj) z2s[r * 66 + c * 4 + jj] = fmaxf(a2[jj], 0.f);
    __syncthreads();

    if (c == 0) {
        float s = fb3[0];
        for (int j = 0; j < 64; ++j) s += z2s[r * 66 + j] * fW3[j];
        out[row] = 1.f / (1.f + __expf(-s));
    }
}

extern "C" void kernel_launch(void* const* d_in, const int* in_sizes, int n_in,
                              void* d_out, int out_size, void* d_ws, size_t ws_size,
                              hipStream_t stream) {
    const int*   item_ids = (const int*)d_in[0];
    const int*   history  = (const int*)d_in[1];
    const int*   hist_len = (const int*)d_in[2];
    const float* emb      = (const float*)d_in[3];
    const float* aW1      = (const float*)d_in[4];
    const float* ab1      = (const float*)d_in[5];
    const float* aW2      = (const float*)d_in[6];
    // d_in[7] = ab2: softmax is shift-invariant, exactly cancels -> unused
    const float* fW1      = (const float*)d_in[8];
    const float* fb1      = (const float*)d_in[9];
    const float* fW2      = (const float*)d_in[10];
    const float* fb2      = (const float*)d_in[11];
    const float* fW3      = (const float*)d_in[12];
    const float* fb3      = (const float*)d_in[13];

    float* comb = (float*)d_ws;   // 4096*192*4 = 3.1 MB

    din_kernel1<<<NB, 256, 0, stream>>>(item_ids, history, hist_len, emb,
                                        aW1, ab1, aW2, comb);
    din_kernel2<<<NB / 16, 256, 0, stream>>>(comb, fW1, fb1, fW2, fb2, fW3, fb3,
                                             (float*)d_out);
}